// Round 1
// baseline (96.679 us; speedup 1.0000x reference)
//
#include <hip/hip_runtime.h>

#define NEG_INF (-1e30f)

typedef __bf16 bf16x8 __attribute__((ext_vector_type(8)));
typedef float  f32x4  __attribute__((ext_vector_type(4)));
typedef unsigned short ushort;

__device__ inline ushort f2bf(float f) {
    union { float f; unsigned u; } v; v.f = f;
    unsigned r = v.u + 0x7fffu + ((v.u >> 16) & 1u);   // round-to-nearest-even
    return (ushort)(r >> 16);
}

__device__ inline float fast_tanhf(float x) {
    // 1 - 2/(1+e^{2x}); saturates correctly for |x| large, ~1e-6 abs err
    return 1.0f - 2.0f / (1.0f + __expf(2.0f * x));
}

// ---------------------------------------------------------------------------
// K0: W_sa [H=512][C=512] fp32 -> Wt [C][H] bf16 (transposed, for B-fragments)
// ---------------------------------------------------------------------------
__global__ void convw_kernel(const float* __restrict__ W, ushort* __restrict__ Wt) {
    int i = blockIdx.x * 256 + threadIdx.x;   // 262144 total
    int h = i >> 9, c = i & 511;
    Wt[c * 512 + h] = f2bf(W[i]);             // W[i] == W[h*512 + c]
}

// ---------------------------------------------------------------------------
// K1: fused GEMM + tanh + w_sc-weighted row reduce -> masked scores [65536]
// Block: 512 thr (8 waves). Tile: M=64 rows x all 512 cols. K-step 32.
// Wave w owns cols [w*64, w*64+64): 4x4 frags of 16x16x32 bf16 MFMA.
// ---------------------------------------------------------------------------
__global__ __launch_bounds__(512) void gemm_scores_kernel(
    const float* __restrict__ feat, const ushort* __restrict__ Wt,
    const float* __restrict__ b_sa, const float* __restrict__ w_sc,
    const float* __restrict__ b_sc, const int* __restrict__ mask,
    float* __restrict__ scores) {

    __shared__ ushort Alds[64 * 40];    // 64 rows x 32 k, pitch 40 (pad: bank spread)
    __shared__ ushort Blds[512 * 40];   // 512 cols x 32 k, pitch 40
    __shared__ float  wpart[8][64];

    const int tid  = threadIdx.x;
    const int m0   = blockIdx.x * 64;
    const int lane = tid & 63;
    const int wv   = tid >> 6;
    const int lr   = lane & 15;          // frag row/col index
    const int lk   = (lane >> 4) * 8;    // frag k start

    f32x4 acc[4][4];
#pragma unroll
    for (int a = 0; a < 4; ++a)
#pragma unroll
        for (int bn = 0; bn < 4; ++bn)
            acc[a][bn] = (f32x4){0.f, 0.f, 0.f, 0.f};

    const int arow = tid >> 3;           // 0..63
    const int acol = (tid & 7) * 4;      // 0..28
    const int brow = tid >> 2;           // 0..127
    const int bcol = (tid & 3) * 8;      // 0..24 (bf16 elems)

    for (int k0 = 0; k0 < 512; k0 += 32) {
        __syncthreads();
        // stage A: 64x32 fp32 -> bf16
        {
            const float4 v = *reinterpret_cast<const float4*>(
                feat + (size_t)(m0 + arow) * 512 + k0 + acol);
            ushort4 bv;
            bv.x = f2bf(v.x); bv.y = f2bf(v.y); bv.z = f2bf(v.z); bv.w = f2bf(v.w);
            *reinterpret_cast<ushort4*>(&Alds[arow * 40 + acol]) = bv;
        }
        // stage B: 512x32 bf16 from Wt (already transposed)
#pragma unroll
        for (int it = 0; it < 4; ++it) {
            int c = it * 128 + brow;
            uint4 raw = *reinterpret_cast<const uint4*>(Wt + (size_t)c * 512 + k0 + bcol);
            *reinterpret_cast<uint4*>(&Blds[c * 40 + bcol]) = raw;
        }
        __syncthreads();

        bf16x8 af[4], bfv[4];
#pragma unroll
        for (int a = 0; a < 4; ++a)
            af[a] = *reinterpret_cast<const bf16x8*>(&Alds[(a * 16 + lr) * 40 + lk]);
#pragma unroll
        for (int bn = 0; bn < 4; ++bn)
            bfv[bn] = *reinterpret_cast<const bf16x8*>(&Blds[(wv * 64 + bn * 16 + lr) * 40 + lk]);
#pragma unroll
        for (int a = 0; a < 4; ++a)
#pragma unroll
            for (int bn = 0; bn < 4; ++bn)
                acc[a][bn] = __builtin_amdgcn_mfma_f32_16x16x32_bf16(
                    af[a], bfv[bn], acc[a][bn], 0, 0, 0);
    }

    // Epilogue: rsum[a][r] = sum over this wave's 64 cols of tanh(C+b_sa)*w_sc
    float rsum[4][4];
#pragma unroll
    for (int a = 0; a < 4; ++a)
#pragma unroll
        for (int r = 0; r < 4; ++r) rsum[a][r] = 0.0f;

#pragma unroll
    for (int bn = 0; bn < 4; ++bn) {
        int c = wv * 64 + bn * 16 + lr;
        float wsc = w_sc[c];
        float bsa = b_sa[c];
#pragma unroll
        for (int a = 0; a < 4; ++a)
#pragma unroll
            for (int r = 0; r < 4; ++r)
                rsum[a][r] += fast_tanhf(acc[a][bn][r] + bsa) * wsc;
    }
    // reduce across the 16 col-lanes (butterfly within low 4 lane bits)
#pragma unroll
    for (int a = 0; a < 4; ++a)
#pragma unroll
        for (int r = 0; r < 4; ++r) {
            float v = rsum[a][r];
            v += __shfl_xor(v, 1);
            v += __shfl_xor(v, 2);
            v += __shfl_xor(v, 4);
            v += __shfl_xor(v, 8);
            rsum[a][r] = v;
        }
    if (lr == 0) {
        int rg = lane >> 4;   // 0..3
#pragma unroll
        for (int a = 0; a < 4; ++a)
#pragma unroll
            for (int r = 0; r < 4; ++r)
                wpart[wv][a * 16 + rg * 4 + r] = rsum[a][r];
    }
    __syncthreads();
    if (tid < 64) {
        float s = b_sc[0];
#pragma unroll
        for (int w2 = 0; w2 < 8; ++w2) s += wpart[w2][tid];
        int m = m0 + tid;
        scores[m] = mask[m] ? s : NEG_INF;
    }
}

// ---------------------------------------------------------------------------
// K2a: per-batch masked softmax, in place on scores (invalid = -1e30 -> p=0)
// ---------------------------------------------------------------------------
__global__ void softmax_kernel(float* __restrict__ scores) {
    int b = blockIdx.x, t = threadIdx.x;  // 256 threads
    float s0 = scores[b * 512 + t];
    float s1 = scores[b * 512 + t + 256];
    float m = fmaxf(s0, s1);
#pragma unroll
    for (int o = 1; o < 64; o <<= 1) m = fmaxf(m, __shfl_xor(m, o));
    __shared__ float red[4];
    if ((t & 63) == 0) red[t >> 6] = m;
    __syncthreads();
    m = fmaxf(fmaxf(red[0], red[1]), fmaxf(red[2], red[3]));
    float e0 = __expf(s0 - m), e1 = __expf(s1 - m);
    float z = e0 + e1;
#pragma unroll
    for (int o = 1; o < 64; o <<= 1) z += __shfl_xor(z, o);
    __syncthreads();
    if ((t & 63) == 0) red[t >> 6] = z;
    __syncthreads();
    float inv = 1.0f / (red[0] + red[1] + red[2] + red[3]);
    scores[b * 512 + t]       = e0 * inv;
    scores[b * 512 + t + 256] = e1 * inv;
}

// ---------------------------------------------------------------------------
// K2b: partial pooled[h] = sum over 64-row n-chunk of p[n]*feat[b,n,h]
// grid (B=128, chunks=8), 256 threads; deterministic (no atomics)
// ---------------------------------------------------------------------------
__global__ void pool_kernel(const float* __restrict__ feat,
                            const float* __restrict__ probs,
                            float* __restrict__ part) {
    int b = blockIdx.x, c = blockIdx.y, t = threadIdx.x;
    __shared__ float pl[64];
    if (t < 64) pl[t] = probs[b * 512 + c * 64 + t];
    __syncthreads();
    const float* fbase = feat + ((size_t)b * 512 + c * 64) * 512;
    float a0 = 0.f, a1 = 0.f;
#pragma unroll 8
    for (int n = 0; n < 64; ++n) {
        float p = pl[n];
        a0 = fmaf(p, fbase[(size_t)n * 512 + t], a0);
        a1 = fmaf(p, fbase[(size_t)n * 512 + t + 256], a1);
    }
    part[(size_t)c * 65536 + b * 512 + t]       = a0;
    part[(size_t)c * 65536 + b * 512 + t + 256] = a1;
}

// ---------------------------------------------------------------------------
// K2c: out = tanh(sum of 8 partials)
// ---------------------------------------------------------------------------
__global__ void finish_kernel(const float* __restrict__ part, float* __restrict__ out) {
    int i = blockIdx.x * 256 + threadIdx.x;
    float s = 0.f;
#pragma unroll
    for (int c = 0; c < 8; ++c) s += part[(size_t)c * 65536 + i];
    out[i] = fast_tanhf(s);
}

extern "C" void kernel_launch(void* const* d_in, const int* in_sizes, int n_in,
                              void* d_out, int out_size, void* d_ws, size_t ws_size,
                              hipStream_t stream) {
    const float* feat = (const float*)d_in[0];
    const int*   mask = (const int*)d_in[1];
    const float* W_sa = (const float*)d_in[2];
    const float* b_sa = (const float*)d_in[3];
    const float* w_sc = (const float*)d_in[4];
    const float* b_sc = (const float*)d_in[5];
    float* out = (float*)d_out;

    char* ws = (char*)d_ws;
    ushort* Wt    = (ushort*)ws;                          // 524288 B
    float*  scores = (float*)(ws + 524288);               // 262144 B (then probs in place)
    float*  part   = (float*)(ws + 524288 + 262144);      // 2 MB

    hipLaunchKernelGGL(convw_kernel, dim3(1024), dim3(256), 0, stream, W_sa, Wt);
    hipLaunchKernelGGL(gemm_scores_kernel, dim3(1024), dim3(512), 0, stream,
                       feat, Wt, b_sa, w_sc, b_sc, mask, scores);
    hipLaunchKernelGGL(softmax_kernel, dim3(128), dim3(256), 0, stream, scores);
    hipLaunchKernelGGL(pool_kernel, dim3(128, 8), dim3(256), 0, stream, feat, scores, part);
    hipLaunchKernelGGL(finish_kernel, dim3(256), dim3(256), 0, stream, part, out);
}